// Round 19
// baseline (140.077 us; speedup 1.0000x reference)
//
#include <hip/hip_runtime.h>
#include <hip/hip_bf16.h>
#include <math.h>
#include <type_traits>

#define DIM 1024
#define NH 16
#define HD 64
#define NB 2
#define SEQ 2048

typedef unsigned short u16;
typedef short short8 __attribute__((ext_vector_type(8)));
typedef unsigned short u16x8 __attribute__((ext_vector_type(8)));
typedef unsigned short u16x4v __attribute__((ext_vector_type(4)));
typedef float f32x4 __attribute__((ext_vector_type(4)));

#define LOG2E 1.44269504f

__device__ __forceinline__ u16 f2bf(float f) {
    __hip_bfloat16 h = __float2bfloat16(f);
    return __builtin_bit_cast(u16, h);
}
__device__ __forceinline__ float bf2f(u16 u) {
    return __uint_as_float(((unsigned)u) << 16);
}
// truncating f32->bf16 (P values only: <=0.4% rel err, self-consistent with l)
__device__ __forceinline__ u16 f2bf_trunc(float f) {
    return (u16)(__float_as_uint(f) >> 16);
}
// raw v_exp_f32 (exp2): used ONLY in the attn softmax hot loop (r14-verified).
__device__ __forceinline__ float fast_exp2(float x) {
    float r;
    asm("v_exp_f32 %0, %1" : "=v"(r) : "v"(x));
    return r;
}

// global -> LDS direct async copy, 16B per lane (dest linear per wave).
__device__ __forceinline__ void gload_lds16(const u16* g, u16* l) {
    __builtin_amdgcn_global_load_lds(
        (const __attribute__((address_space(1))) unsigned int*)g,
        (__attribute__((address_space(3))) unsigned int*)l, 16, 0, 0);
}

// ---------------------------------------------------------------------------
// fp32 -> bf16 conversion pass, flat grid (right-sized: 4096 blocks).
// ---------------------------------------------------------------------------
__global__ __launch_bounds__(256)
void conv_bf16(const float* __restrict__ x,
               const float* __restrict__ wq, const float* __restrict__ wk,
               const float* __restrict__ wv, const float* __restrict__ wo,
               u16* __restrict__ xbf, u16* __restrict__ wbf)
{
    const int idx8 = (blockIdx.x * 256 + threadIdx.x) * 8;
    const float* src; u16* dst; int off;
    if (idx8 < (1 << 22)) {
        src = x; dst = xbf; off = idx8;
    } else {
        const int wi  = idx8 - (1 << 22);
        const int sel = wi >> 20;
        src = (sel == 0) ? wq : (sel == 1) ? wk : (sel == 2) ? wv : wo;
        dst = wbf + ((size_t)sel << 20);
        off = wi & ((1 << 20) - 1);
    }
    float4 a = *(const float4*)(src + off);
    float4 b = *(const float4*)(src + off + 4);
    u16x8 o;
    o[0] = f2bf(a.x); o[1] = f2bf(a.y); o[2] = f2bf(a.z); o[3] = f2bf(a.w);
    o[4] = f2bf(b.x); o[5] = f2bf(b.y); o[6] = f2bf(b.z); o[7] = f2bf(b.w);
    *(u16x8*)(dst + off) = o;
}

// ---------------------------------------------------------------------------
// bf16 GEMM via global_load_lds (m97 structure). r18-identical.
// MODE 0: z=0(q)/1(k) head-split [b,h,s,hd] bf16; z=2(v) transposed [b,h,d,s].
// MODE 1: fp32 flat [b,s,e]; blockIdx.y==8 & x<32 -> fused memwrite_reduce.
// ---------------------------------------------------------------------------
template<int MODE, int FM>
__global__ __launch_bounds__(256)
void gemm_lds(const u16* __restrict__ X, const u16* __restrict__ Wall,
              u16* __restrict__ Obf, float* __restrict__ Of,
              const float* __restrict__ part, const float* __restrict__ pnorm,
              const float* __restrict__ memv, const float* __restrict__ normv,
              float* __restrict__ new_mem, float* __restrict__ new_norm)
{
    constexpr int MT = FM * 32;
    __shared__ u16 As[MT * 64];
    __shared__ u16 Bs[128 * 64];

    if (MODE == 1 && blockIdx.y == 8) {
        if (blockIdx.x >= 32) return;
        const int bh = blockIdx.x;
        const int t  = threadIdx.x;
        #pragma unroll
        for (int u = 0; u < 16; ++u) {
            const int fl = t + (u << 8);
            float s = memv[(size_t)bh * 4096 + fl];
            #pragma unroll
            for (int ch = 0; ch < 16; ++ch)
                s += part[((size_t)bh * 16 + ch) * 4096 + fl];
            new_mem[(size_t)bh * 4096 + fl] = s;
        }
        if (t < 64) {
            float s = normv[(size_t)bh * 64 + t];
            #pragma unroll
            for (int ch = 0; ch < 16; ++ch)
                s += pnorm[((size_t)bh * 16 + ch) * 64 + t];
            new_norm[(size_t)bh * 64 + t] = s;
        }
        return;
    }

    const int t    = threadIdx.x;
    const int lane = t & 63;
    const int wave = t >> 6;
    const int wm = wave >> 1, wn = wave & 1;
    const int lr = lane & 15, kg = lane >> 4;
    const int m_base = blockIdx.x * MT;
    const int n_base = blockIdx.y * 128;

    const u16* Xb = X + (size_t)m_base * DIM;
    const u16* Wb = Wall + (MODE == 0 ? ((size_t)blockIdx.z << 20) : (size_t)0)
                         + (size_t)n_base * DIM;

    f32x4 acc[FM][4];
    #pragma unroll
    for (int i = 0; i < FM; ++i)
        #pragma unroll
        for (int j = 0; j < 4; ++j) {
            f32x4 z = {0.f, 0.f, 0.f, 0.f};
            acc[i][j] = z;
        }

    for (int k0 = 0; k0 < DIM; k0 += 64) {
        __syncthreads();
        #pragma unroll
        for (int u = 0; u < FM; ++u) {
            const int cid = (u << 8) + t;
            const int row = cid >> 3, c16 = cid & 7;
            const int src = c16 ^ (row & 7);
            gload_lds16(Xb + (size_t)row * DIM + k0 + (src << 3), &As[cid << 3]);
        }
        #pragma unroll
        for (int u = 0; u < 4; ++u) {
            const int cid = (u << 8) + t;
            const int row = cid >> 3, c16 = cid & 7;
            const int src = c16 ^ (row & 7);
            gload_lds16(Wb + (size_t)row * DIM + k0 + (src << 3), &Bs[cid << 3]);
        }
        __syncthreads();

        #pragma unroll
        for (int kh = 0; kh < 2; ++kh) {
            short8 afrag[FM], bfrag[4];
            #pragma unroll
            for (int fm = 0; fm < FM; ++fm) {
                const int r = wm * (FM * 16) + fm * 16 + lr;
                const int c = (kh << 2) + kg;
                afrag[fm] = *(const short8*)&As[r * 64 + (((c) ^ (r & 7)) << 3)];
            }
            #pragma unroll
            for (int fn = 0; fn < 4; ++fn) {
                const int r = wn * 64 + fn * 16 + lr;
                const int c = (kh << 2) + kg;
                bfrag[fn] = *(const short8*)&Bs[r * 64 + (((c) ^ (r & 7)) << 3)];
            }
            #pragma unroll
            for (int fm = 0; fm < FM; ++fm)
                #pragma unroll
                for (int fn = 0; fn < 4; ++fn)
                    acc[fm][fn] = __builtin_amdgcn_mfma_f32_16x16x32_bf16(
                        afrag[fm], bfrag[fn], acc[fm][fn], 0, 0, 0);
        }
    }

    u16* O0 = (MODE == 0) ? Obf + ((size_t)blockIdx.z << 22) : nullptr;
    if (MODE == 0 && blockIdx.z == 2) {
        #pragma unroll
        for (int fm = 0; fm < FM; ++fm) {
            const int m0 = m_base + wm * (FM * 16) + fm * 16 + kg * 4;
            const int b_ = m0 >> 11;
            const int s0 = m0 & (SEQ - 1);
            #pragma unroll
            for (int fn = 0; fn < 4; ++fn) {
                const int n  = n_base + wn * 64 + fn * 16 + lr;
                const int h_ = n >> 6, d_ = n & 63;
                u16x4v pk;
                #pragma unroll
                for (int i = 0; i < 4; ++i) pk[i] = f2bf(acc[fm][fn][i]);
                *(u16x4v*)(O0 + (((size_t)b_ * NH + h_) * HD + d_) * SEQ + s0) = pk;
            }
        }
    } else {
        #pragma unroll
        for (int fm = 0; fm < FM; ++fm) {
            const int mrow0 = m_base + wm * (FM * 16) + fm * 16 + kg * 4;
            #pragma unroll
            for (int i = 0; i < 4; ++i) {
                const int m = mrow0 + i;
                const int b = m >> 11;
                const int s = m & (SEQ - 1);
                #pragma unroll
                for (int fn = 0; fn < 4; ++fn) {
                    const int n = n_base + wn * 64 + fn * 16 + lr;
                    const float val = acc[fm][fn][i];
                    if (MODE == 0)
                        O0[(((size_t)b * NH + (n >> 6)) * SEQ + s) * HD + (n & 63)] =
                            f2bf(val);
                    else
                        Of[((size_t)b * SEQ + s) * DIM + n] = val;
                }
            }
        }
    }
}

// ---------------------------------------------------------------------------
// MFMA flash attention, 8-WAVE FM-SPLIT: 512 thr; waves 0-3 own qa's four
// 16-row slices, waves 4-7 own qb's. The two fm computations (serial per
// wave in r17) now run in parallel across waves -> per-tile critical path
// ~1.5x shorter at equal waves/CU; per-wave state halves (oacc[4], one
// qatt/qmem) so the register allocation can drop toward the 128 granule,
// allowing 2 blocks/CU (16 waves). fm0 waves skip compute past kt>qa but
// join staging + barriers (wave-uniform). Staging = 1 gload/thread;
// boundary waits vmcnt(2) (K+V of tile kt+2 in flight). Data path otherwise
// r14/r17-verbatim (m=0, ones-column l, 3-slot KV, v_exp_f32 softmax).
// __launch_bounds__(512,2) permissive (r6: never force below natural budget).
// Tripwires: WRITE_SIZE 8192 (no spill), conflicts 0.
// ---------------------------------------------------------------------------
__global__ __launch_bounds__(512, 2)
void attn_mfma(const u16* __restrict__ q,
               const u16* __restrict__ k,
               const u16* __restrict__ vt,
               const float* __restrict__ memv,
               const float* __restrict__ normv,
               const float* __restrict__ gatev,
               u16* __restrict__ comb)
{
    __shared__ u16 Ks[3][64 * 64];
    __shared__ u16 Vs[3][64 * 64];
    __shared__ u16 Ps[8 * 16 * 64];   // 16KB per-wave P; aliases norm_s / Mt

    const int t    = threadIdx.x;     // 0..511
    const int lane = t & 63;
    const int w    = t >> 6;          // 0..7
    const int lr   = lane & 15;
    const int kg   = lane >> 4;

    // XCD-grouped bijection: xcd x hosts bh in {x, x+8, x+16, x+24}
    const int lin  = blockIdx.x + 16 * blockIdx.y + 256 * blockIdx.z;  // 0..511
    const int x    = lin & 7;
    const int gg   = lin >> 3;
    const int bh_i = x + 8 * (gg & 3);
    const int p    = gg >> 2;          // 0..15
    const int h    = bh_i & 15;
    const int b    = bh_i >> 4;
    const int qa = p, qb = 31 - p;
    const int nkt = qb + 1;

    const int fm  = w >> 2;            // 0: qa-group, 1: qb-group
    const int w4  = w & 3;
    const int myq = fm ? qb : qa;
    const int rb  = myq * 64 + w4 * 16;

    const size_t bh = (size_t)b * NH + h;
    const u16* qp  = q  + bh * SEQ * HD;
    const u16* kp  = k  + bh * SEQ * HD;
    const u16* vtp = vt + bh * SEQ * HD;   // [d][s]

    // ---- hoisted loop-invariant LDS offsets (u16 units) ----
    int koff[4][2];
    #pragma unroll
    for (int fn = 0; fn < 4; ++fn)
        #pragma unroll
        for (int kk = 0; kk < 2; ++kk) {
            const int r = fn * 16 + lr;
            koff[fn][kk] = r * 64 + ((((kk << 2) + kg) ^ (r & 7)) << 3);
        }
    int pwoff[4][4];
    #pragma unroll
    for (int r = 0; r < 4; ++r) {
        const int row_p = kg * 4 + r;
        const int base_r = w * 1024 + row_p * 64 + (lr & 7);
        #pragma unroll
        for (int fn = 0; fn < 4; ++fn)
            pwoff[r][fn] = base_r + ((((fn << 1) + (lr >> 3)) ^ (row_p & 7)) << 3);
    }
    int pfoff[2];
    #pragma unroll
    for (int kk = 0; kk < 2; ++kk)
        pfoff[kk] = w * 1024 + lr * 64 + ((((kk << 2) + kg) ^ (lr & 7)) << 3);

    // staging with 512 threads: one 16B gload per thread per buffer
    auto stageK = [&](int kt, u16* dst) {
        const int row = t >> 3, c16 = t & 7;
        const int src = c16 ^ (row & 7);
        gload_lds16(kp + (size_t)(kt * 64 + row) * HD + (src << 3),
                    dst + (t << 3));
    };
    auto stageV = [&](int kt, u16* dst) {
        const int row = t >> 3, c16 = t & 7;
        const int src = c16 ^ (row & 7);
        gload_lds16(vtp + (size_t)row * SEQ + kt * 64 + (src << 3),
                    dst + (t << 3));
    };

    // ---- stage norm into Ps alias ----
    float* norm_s = (float*)Ps;
    if (t < 64) norm_s[t] = normv[bh * HD + t];
    __syncthreads();

    // ---- Q prologue (single fm per wave) ----
    short8 qatt[2], qmem[2];
    float nrrow;
    {
        const u16* qrow = qp + (size_t)(rb + lr) * HD;
        float nr = 0.f;
        #pragma unroll
        for (int kk = 0; kk < 2; ++kk) {
            const int dbase = kk * 32 + kg * 8;
            u16x8 raw = *(const u16x8*)(qrow + dbase);
            short8 sa, sm;
            #pragma unroll
            for (int i = 0; i < 8; ++i) {
                const float xx = bf2f(raw[i]);
                sa[i] = (short)f2bf(xx * (0.125f * LOG2E));
                const float e = (xx > 0.f) ? (xx + 1.f) : __expf(xx);
                sm[i] = (short)f2bf(e);
                nr = fmaf(e, norm_s[dbase + i], nr);
            }
            qatt[kk] = sa; qmem[kk] = sm;
        }
        nr += __shfl_xor(nr, 16);
        nr += __shfl_xor(nr, 32);
        nrrow = nr;
    }

    // ones B-frag: lr==0 holds ones row -> lacc col 0 = row sums of P
    short8 ones8;
    {
        const short o = (lr == 0) ? (short)0x3F80 : (short)0;
        #pragma unroll
        for (int i = 0; i < 8; ++i) ones8[i] = o;
    }

    f32x4 oacc[4], lacc;
    #pragma unroll
    for (int fn = 0; fn < 4; ++fn) {
        f32x4 z = {0.f, 0.f, 0.f, 0.f};
        oacc[fn] = z;
    }
    { f32x4 z = {0.f, 0.f, 0.f, 0.f}; lacc = z; }

    // ---- prologue staging: tiles 0 and 1 (2 loads each) ----
    stageK(0, &Ks[0][0]);
    stageV(0, &Vs[0][0]);
    stageK(1, &Ks[1][0]);
    stageV(1, &Vs[1][0]);
    asm volatile("s_waitcnt vmcnt(2)" ::: "memory");  // tile0 landed
    __builtin_amdgcn_sched_barrier(0);
    __builtin_amdgcn_s_barrier();

    // ---- main KV loop: counted-vmcnt boundaries, 3 KV slots ----
    int cur = 0;   // slot of tile kt
    for (int kt = 0; kt < nkt; ++kt) {
        const u16* Kc = &Ks[cur][0];
        const u16* Vc = &Vs[cur][0];
        const int sl2 = (cur == 0) ? 2 : cur - 1;   // slot (kt+2)%3

        const bool more2 = (kt + 2 < nkt);
        if (more2) {
            stageK(kt + 2, &Ks[sl2][0]);
            stageV(kt + 2, &Vs[sl2][0]);
        }

        if (kt <= myq) {
            short8 kf[4][2], vf[4][2];
            #pragma unroll
            for (int fn = 0; fn < 4; ++fn)
                #pragma unroll
                for (int kk = 0; kk < 2; ++kk) {
                    kf[fn][kk] = *(const short8*)&Kc[koff[fn][kk]];
                    vf[fn][kk] = *(const short8*)&Vc[koff[fn][kk]];
                }

            const bool diag = (kt == myq);
            f32x4 S[4];
            #pragma unroll
            for (int fn = 0; fn < 4; ++fn) {
                f32x4 z = {0.f, 0.f, 0.f, 0.f};
                S[fn] = z;
            }
            __builtin_amdgcn_s_setprio(1);
            #pragma unroll
            for (int fn = 0; fn < 4; ++fn)
                #pragma unroll
                for (int kk = 0; kk < 2; ++kk)
                    S[fn] = __builtin_amdgcn_mfma_f32_16x16x32_bf16(
                        qatt[kk], kf[fn][kk], S[fn], 0, 0, 0);
            __builtin_amdgcn_s_setprio(0);

            #pragma unroll
            for (int fn = 0; fn < 4; ++fn) {
                const int kgl = kt * 64 + fn * 16 + lr;
                #pragma unroll
                for (int r = 0; r < 4; ++r) {
                    float pe = fast_exp2(S[fn][r]);
                    if (diag && kgl > rb + kg * 4 + r) pe = 0.f;
                    Ps[pwoff[r][fn]] = f2bf_trunc(pe);
                }
            }

            short8 pf[2];
            #pragma unroll
            for (int kk = 0; kk < 2; ++kk)
                pf[kk] = *(const short8*)&Ps[pfoff[kk]];
            __builtin_amdgcn_s_setprio(1);
            #pragma unroll
            for (int fnd = 0; fnd < 4; ++fnd)
                #pragma unroll
                for (int kk = 0; kk < 2; ++kk)
                    oacc[fnd] = __builtin_amdgcn_mfma_f32_16x16x32_bf16(
                        pf[kk], vf[fnd][kk], oacc[fnd], 0, 0, 0);
            #pragma unroll
            for (int kk = 0; kk < 2; ++kk)
                lacc = __builtin_amdgcn_mfma_f32_16x16x32_bf16(
                    pf[kk], ones8, lacc, 0, 0, 0);
            __builtin_amdgcn_s_setprio(0);
        }

        // boundary: tile kt+1's loads must have landed; kt+2's stay in flight
        if (more2) {
            asm volatile("s_waitcnt vmcnt(2)" ::: "memory");
        } else {
            asm volatile("s_waitcnt vmcnt(0)" ::: "memory");
        }
        __builtin_amdgcn_sched_barrier(0);
        __builtin_amdgcn_s_barrier();

        cur = (cur == 2) ? 0 : cur + 1;
    }

    // ---- epilogue: restage M (transposed, swizzled) into Ps region ----
    u16* MtS = Ps;
    {
        const float* Mb = memv + bh * HD * HD;
        const int gd = t & 63;             // 512 thr x 8 elems = 4096
        const int e0 = (t >> 6) << 3;
        float4 m0 = *(const float4*)(Mb + gd * HD + e0);
        float4 m1 = *(const float4*)(Mb + gd * HD + e0 + 4);
        float mv8[8];
        *(float4*)&mv8[0] = m0; *(float4*)&mv8[4] = m1;
        const int a = gd >> 3, bse = gd & 7;
        #pragma unroll
        for (int j = 0; j < 8; ++j)
            MtS[(e0 + j) * 64 + ((a ^ j) << 3) + bse] = f2bf(mv8[j]);
    }
    __syncthreads();

    short8 mf2[4][2];
    #pragma unroll
    for (int fn = 0; fn < 4; ++fn)
        #pragma unroll
        for (int kk = 0; kk < 2; ++kk)
            mf2[fn][kk] = *(const short8*)&MtS[koff[fn][kk]];

    const float gte = gatev[h];
    const float g  = 1.f / (1.f + __expf(-gte));
    const float og = 1.f - g;

    f32x4 macc[4];
    #pragma unroll
    for (int fn = 0; fn < 4; ++fn) {
        f32x4 z = {0.f, 0.f, 0.f, 0.f};
        macc[fn] = z;
        #pragma unroll
        for (int kk = 0; kk < 2; ++kk)
            macc[fn] = __builtin_amdgcn_mfma_f32_16x16x32_bf16(
                qmem[kk], mf2[fn][kk], macc[fn], 0, 0, 0);
    }

    #pragma unroll
    for (int r = 0; r < 4; ++r) {
        const int rt  = kg * 4 + r;
        const float lsum  = __shfl(lacc[r], lane & 48);
        const float linv  = 1.f / lsum;
        const float nrd   = __shfl(nrrow, (lane & 48) | rt);
        const float nrinv = 1.f / (nrd + 1e-6f);
        const int qg = rb + rt;
        u16* crow = comb + ((size_t)b * SEQ + qg) * DIM + h * HD;
        #pragma unroll
        for (int fn = 0; fn < 4; ++fn)
            crow[fn * 16 + lr] = f2bf(
                g * (macc[fn][r] * nrinv) + og * (oacc[fn][r] * linv));
    }
}

// ---------------------------------------------------------------------------
// Memory write partials via MFMA. r18-identical.
// ---------------------------------------------------------------------------
__global__ __launch_bounds__(256)
void memwrite_mfma(const u16* __restrict__ k,
                   const u16* __restrict__ vt,
                   float* __restrict__ part,
                   float* __restrict__ pnorm)
{
    __shared__ u16 KelT[64 * 64];
    __shared__ u16 Vs[64 * 64];

    const int ch = blockIdx.x;   // 0..15 (128-s chunk)
    const int bh = blockIdx.y;   // 0..31
    const int t    = threadIdx.x;
    const int lane = t & 63;
    const int w    = t >> 6;
    const int lr   = lane & 15;
    const int kg   = lane >> 4;

    const u16* kb  = k  + (size_t)bh * SEQ * HD + (size_t)ch * 128 * HD;
    const u16* vtb = vt + (size_t)bh * SEQ * HD + (size_t)ch * 128;   // [d][s]

    int aoff[2];
    #pragma unroll
    for (int kk = 0; kk < 2; ++kk) {
        const int r = w * 16 + lr;
        aoff[kk] = r * 64 + ((((kk << 2) + kg) ^ (r & 7)) << 3);
    }
    int boff[4][2];
    #pragma unroll
    for (int fn = 0; fn < 4; ++fn)
        #pragma unroll
        for (int kk = 0; kk < 2; ++kk) {
            const int r = fn * 16 + lr;
            boff[fn][kk] = r * 64 + ((((kk << 2) + kg) ^ (r & 7)) << 3);
        }

    short8 ones8;
    {
        const short o = (lr == 0) ? (short)0x3F80 : (short)0;
        #pragma unroll
        for (int i = 0; i < 8; ++i) ones8[i] = o;
    }

    f32x4 acc[4], lacc;
    #pragma unroll
    for (int fn = 0; fn < 4; ++fn) {
        f32x4 z = {0.f, 0.f, 0.f, 0.f};
        acc[fn] = z;
    }
    { f32x4 z = {0.f, 0.f, 0.f, 0.f}; lacc = z; }

    for (int st = 0; st < 2; ++st) {
        __syncthreads();
        #pragma unroll
        for (int u = 0; u < 2; ++u) {
            const int cid = (u << 8) + t;
            const int row = cid >> 3, c16 = cid & 7;
            const int src = c16 ^ (row & 7);
            gload_lds16(vtb + (size_t)row * SEQ + st * 64 + (src << 3),
                        &Vs[cid << 3]);
        }
        #pragma unroll
        for (int u = 0; u < 2; ++u) {
            const int cid = (u << 8) + t;
            const int krow = cid & 63;
            const int d0   = (cid >> 6) << 3;
            u16x8 kv = *(const u16x8*)(kb + (size_t)(st * 64 + krow) * HD + d0);
            const int a = krow >> 3, bse = krow & 7;
            #pragma unroll
            for (int j = 0; j < 8; ++j) {
                const float kf = bf2f(kv[j]);
                const float e = (kf > 0.f) ? kf + 1.f : __expf(kf);
                KelT[(d0 + j) * 64 + ((a ^ ((d0 + j) & 7)) << 3) + bse] = f2bf(e);
            }
        }
        __syncthreads();

        short8 af[2];
        #pragma unroll
        for (int kk = 0; kk < 2; ++kk)
            af[kk] = *(const short8*)&KelT[aoff[kk]];
        #pragma unroll
        for (int fn = 0; fn < 4; ++fn)
            #pragma unroll
            for (int kk = 0; kk < 2; ++kk) {
                short8 bfv = *(const short8*)&Vs[boff[fn][kk]];
                acc[fn] = __builtin_amdgcn_mfma_f32_16x16x32_bf16(
                    af[kk], bfv, acc[fn], 0, 0, 0);
            }
        #pragma unroll
        for (int kk = 0; kk < 2; ++kk)
            lacc = __builtin_amdgcn_mfma_f32_16x16x32_bf16(
                af[kk], ones8, lacc, 0, 0, 0);
    }

    float* po = part + ((size_t)bh * 16 + ch) * 4096;
    #pragma unroll
    for (int r = 0; r < 4; ++r) {
        const int d = w * 16 + kg * 4 + r;
        #pragma unroll
        for (int fn = 0; fn < 4; ++fn)
            po[d * 64 + fn * 16 + lr] = acc[fn][r];
    }
    if (lr == 0) {
        #pragma unroll
        for (int r = 0; r < 4; ++r)
            pnorm[((size_t)bh * 16 + ch) * 64 + w * 16 + kg * 4 + r] = lacc[r];
    }
}

// ---------------------------------------------------------------------------
extern "C" void kernel_launch(void* const* d_in, const int* in_sizes, int n_in,
                              void* d_out, int out_size, void* d_ws, size_t ws_size,
                              hipStream_t stream)
{
    const float* x     = (const float*)d_in[0];
    const float* memv  = (const float*)d_in[1];
    const float* normv = (const float*)d_in[2];
    const float* Wq    = (const float*)d_in[3];
    const float* Wk    = (const float*)d_in[4];
    const float* Wv    = (const float*)d_in[5];
    const float* Wo    = (const float*)d_in[6];
    const float* gate  = (const float*)d_in[7];
    float* out = (float*)d_out;

    u16* xbf  = (u16*)d_ws;                    // 2^22 elems
    u16* wbf  = xbf + ((size_t)1 << 22);       // 4 * 2^20
    u16* qkv  = wbf + ((size_t)4 << 20);       // 3 * 2^22 (q, k, vT)
    u16* comb = qkv + ((size_t)3 << 22);       // 2^22
    float* part  = (float*)(comb + ((size_t)1 << 22));   // 2^21 f32 (8 MB)
    float* pnorm = part + ((size_t)1 << 21);             // 32768 f32

    u16* qbf = qkv;
    u16* kbf = qkv + ((size_t)1 << 22);
    u16* vtb = qkv + ((size_t)2 << 22);        // V^T [b,h,d,s]

    float* new_mem  = out + (size_t)NB * SEQ * DIM;
    float* new_norm = new_mem + (size_t)NB * NH * HD * HD;

    conv_bf16<<<dim3(4096), 256, 0, stream>>>(x, Wq, Wk, Wv, Wo, xbf, wbf);
    gemm_lds<0, 4><<<dim3(32, 8, 3), 256, 0, stream>>>(
        xbf, wbf, qkv, nullptr,
        nullptr, nullptr, nullptr, nullptr, nullptr, nullptr);
    attn_mfma<<<dim3(16, 16, 2), 512, 0, stream>>>(qbf, kbf, vtb, memv, normv,
                                                   gate, comb);
    memwrite_mfma<<<dim3(16, 32), 256, 0, stream>>>(kbf, vtb, part, pnorm);
    gemm_lds<1, 2><<<dim3(64, 9, 1), 256, 0, stream>>>(
        comb, wbf + ((size_t)3 << 20), nullptr, out,
        part, pnorm, memv, normv, new_mem, new_norm);
}

// Round 20
// 116.510 us; speedup vs baseline: 1.2023x; 1.2023x over previous
//
#include <hip/hip_runtime.h>
#include <hip/hip_bf16.h>
#include <math.h>
#include <type_traits>

#define DIM 1024
#define NH 16
#define HD 64
#define NB 2
#define SEQ 2048

typedef unsigned short u16;
typedef short short8 __attribute__((ext_vector_type(8)));
typedef unsigned short u16x8 __attribute__((ext_vector_type(8)));
typedef unsigned short u16x4v __attribute__((ext_vector_type(4)));
typedef float f32x4 __attribute__((ext_vector_type(4)));

#define LOG2E 1.44269504f

__device__ __forceinline__ u16 f2bf(float f) {
    __hip_bfloat16 h = __float2bfloat16(f);
    return __builtin_bit_cast(u16, h);
}
__device__ __forceinline__ float bf2f(u16 u) {
    return __uint_as_float(((unsigned)u) << 16);
}
// truncating f32->bf16 (P values only: <=0.4% rel err, self-consistent with l)
__device__ __forceinline__ u16 f2bf_trunc(float f) {
    return (u16)(__float_as_uint(f) >> 16);
}
// raw v_exp_f32 (exp2): used ONLY in the attn softmax hot loop (r14-verified).
__device__ __forceinline__ float fast_exp2(float x) {
    float r;
    asm("v_exp_f32 %0, %1" : "=v"(r) : "v"(x));
    return r;
}

// global -> LDS direct async copy, 16B per lane (dest linear per wave).
__device__ __forceinline__ void gload_lds16(const u16* g, u16* l) {
    __builtin_amdgcn_global_load_lds(
        (const __attribute__((address_space(1))) unsigned int*)g,
        (__attribute__((address_space(3))) unsigned int*)l, 16, 0, 0);
}

// ---------------------------------------------------------------------------
// fp32 -> bf16 conversion pass, flat grid (right-sized: 4096 blocks).
// ---------------------------------------------------------------------------
__global__ __launch_bounds__(256)
void conv_bf16(const float* __restrict__ x,
               const float* __restrict__ wq, const float* __restrict__ wk,
               const float* __restrict__ wv, const float* __restrict__ wo,
               u16* __restrict__ xbf, u16* __restrict__ wbf)
{
    const int idx8 = (blockIdx.x * 256 + threadIdx.x) * 8;
    const float* src; u16* dst; int off;
    if (idx8 < (1 << 22)) {
        src = x; dst = xbf; off = idx8;
    } else {
        const int wi  = idx8 - (1 << 22);
        const int sel = wi >> 20;
        src = (sel == 0) ? wq : (sel == 1) ? wk : (sel == 2) ? wv : wo;
        dst = wbf + ((size_t)sel << 20);
        off = wi & ((1 << 20) - 1);
    }
    float4 a = *(const float4*)(src + off);
    float4 b = *(const float4*)(src + off + 4);
    u16x8 o;
    o[0] = f2bf(a.x); o[1] = f2bf(a.y); o[2] = f2bf(a.z); o[3] = f2bf(a.w);
    o[4] = f2bf(b.x); o[5] = f2bf(b.y); o[6] = f2bf(b.z); o[7] = f2bf(b.w);
    *(u16x8*)(dst + off) = o;
}

// ---------------------------------------------------------------------------
// bf16 GEMM via global_load_lds (m97 structure).
// MODE 0: z=0(q)/1(k) head-split [b,h,s,hd] bf16; z=2(v) transposed [b,h,d,s].
// MODE 1: fp32 flat [b,s,e]; blockIdx.y==8 & x<32 -> fused memwrite_reduce
// (16 chunks). Wo uses FM=2 grid(64,9) — r16: FM=4 @256 blocks lost ~10us.
// ---------------------------------------------------------------------------
template<int MODE, int FM>
__global__ __launch_bounds__(256)
void gemm_lds(const u16* __restrict__ X, const u16* __restrict__ Wall,
              u16* __restrict__ Obf, float* __restrict__ Of,
              const float* __restrict__ part, const float* __restrict__ pnorm,
              const float* __restrict__ memv, const float* __restrict__ normv,
              float* __restrict__ new_mem, float* __restrict__ new_norm)
{
    constexpr int MT = FM * 32;
    __shared__ u16 As[MT * 64];
    __shared__ u16 Bs[128 * 64];

    if (MODE == 1 && blockIdx.y == 8) {
        if (blockIdx.x >= 32) return;
        const int bh = blockIdx.x;
        const int t  = threadIdx.x;
        #pragma unroll
        for (int u = 0; u < 16; ++u) {
            const int fl = t + (u << 8);
            float s = memv[(size_t)bh * 4096 + fl];
            #pragma unroll
            for (int ch = 0; ch < 16; ++ch)
                s += part[((size_t)bh * 16 + ch) * 4096 + fl];
            new_mem[(size_t)bh * 4096 + fl] = s;
        }
        if (t < 64) {
            float s = normv[(size_t)bh * 64 + t];
            #pragma unroll
            for (int ch = 0; ch < 16; ++ch)
                s += pnorm[((size_t)bh * 16 + ch) * 64 + t];
            new_norm[(size_t)bh * 64 + t] = s;
        }
        return;
    }

    const int t    = threadIdx.x;
    const int lane = t & 63;
    const int wave = t >> 6;
    const int wm = wave >> 1, wn = wave & 1;
    const int lr = lane & 15, kg = lane >> 4;
    const int m_base = blockIdx.x * MT;
    const int n_base = blockIdx.y * 128;

    const u16* Xb = X + (size_t)m_base * DIM;
    const u16* Wb = Wall + (MODE == 0 ? ((size_t)blockIdx.z << 20) : (size_t)0)
                         + (size_t)n_base * DIM;

    f32x4 acc[FM][4];
    #pragma unroll
    for (int i = 0; i < FM; ++i)
        #pragma unroll
        for (int j = 0; j < 4; ++j) {
            f32x4 z = {0.f, 0.f, 0.f, 0.f};
            acc[i][j] = z;
        }

    for (int k0 = 0; k0 < DIM; k0 += 64) {
        __syncthreads();
        #pragma unroll
        for (int u = 0; u < FM; ++u) {
            const int cid = (u << 8) + t;
            const int row = cid >> 3, c16 = cid & 7;
            const int src = c16 ^ (row & 7);
            gload_lds16(Xb + (size_t)row * DIM + k0 + (src << 3), &As[cid << 3]);
        }
        #pragma unroll
        for (int u = 0; u < 4; ++u) {
            const int cid = (u << 8) + t;
            const int row = cid >> 3, c16 = cid & 7;
            const int src = c16 ^ (row & 7);
            gload_lds16(Wb + (size_t)row * DIM + k0 + (src << 3), &Bs[cid << 3]);
        }
        __syncthreads();

        #pragma unroll
        for (int kh = 0; kh < 2; ++kh) {
            short8 afrag[FM], bfrag[4];
            #pragma unroll
            for (int fm = 0; fm < FM; ++fm) {
                const int r = wm * (FM * 16) + fm * 16 + lr;
                const int c = (kh << 2) + kg;
                afrag[fm] = *(const short8*)&As[r * 64 + (((c) ^ (r & 7)) << 3)];
            }
            #pragma unroll
            for (int fn = 0; fn < 4; ++fn) {
                const int r = wn * 64 + fn * 16 + lr;
                const int c = (kh << 2) + kg;
                bfrag[fn] = *(const short8*)&Bs[r * 64 + (((c) ^ (r & 7)) << 3)];
            }
            #pragma unroll
            for (int fm = 0; fm < FM; ++fm)
                #pragma unroll
                for (int fn = 0; fn < 4; ++fn)
                    acc[fm][fn] = __builtin_amdgcn_mfma_f32_16x16x32_bf16(
                        afrag[fm], bfrag[fn], acc[fm][fn], 0, 0, 0);
        }
    }

    u16* O0 = (MODE == 0) ? Obf + ((size_t)blockIdx.z << 22) : nullptr;
    if (MODE == 0 && blockIdx.z == 2) {
        #pragma unroll
        for (int fm = 0; fm < FM; ++fm) {
            const int m0 = m_base + wm * (FM * 16) + fm * 16 + kg * 4;
            const int b_ = m0 >> 11;
            const int s0 = m0 & (SEQ - 1);
            #pragma unroll
            for (int fn = 0; fn < 4; ++fn) {
                const int n  = n_base + wn * 64 + fn * 16 + lr;
                const int h_ = n >> 6, d_ = n & 63;
                u16x4v pk;
                #pragma unroll
                for (int i = 0; i < 4; ++i) pk[i] = f2bf(acc[fm][fn][i]);
                *(u16x4v*)(O0 + (((size_t)b_ * NH + h_) * HD + d_) * SEQ + s0) = pk;
            }
        }
    } else {
        #pragma unroll
        for (int fm = 0; fm < FM; ++fm) {
            const int mrow0 = m_base + wm * (FM * 16) + fm * 16 + kg * 4;
            #pragma unroll
            for (int i = 0; i < 4; ++i) {
                const int m = mrow0 + i;
                const int b = m >> 11;
                const int s = m & (SEQ - 1);
                #pragma unroll
                for (int fn = 0; fn < 4; ++fn) {
                    const int n = n_base + wn * 64 + fn * 16 + lr;
                    const float val = acc[fm][fn][i];
                    if (MODE == 0)
                        O0[(((size_t)b * NH + (n >> 6)) * SEQ + s) * HD + (n & 63)] =
                            f2bf(val);
                    else
                        Of[((size_t)b * SEQ + s) * DIM + n] = val;
                }
            }
        }
    }
}

// ---------------------------------------------------------------------------
// MFMA flash attention + memory read + gated combine. r17/r18 verbatim
// (256 thr / 4 waves, serial fm-pair qa=p / qb=31-p -> every block exactly
// 33 tile-units, uniform; m=0, ones-column l, 3-slot KV + counted vmcnt(4) +
// raw s_barrier, v_exp_f32 softmax, __expf elu).
// r19 lesson: fm-split across waves breaks block uniformity (time ~ qb+1,
// non-uniform at 2 blocks/CU) + idles half the waves -> +20us. Keep serial.
// r13: no memwrite interleave. r11: 64-stride LDS rows. r10: no KV-split.
// __launch_bounds__(256,2): tighter bounds spill (r6).
// ---------------------------------------------------------------------------
__global__ __launch_bounds__(256, 2)
void attn_mfma(const u16* __restrict__ q,
               const u16* __restrict__ k,
               const u16* __restrict__ vt,
               const float* __restrict__ memv,
               const float* __restrict__ normv,
               const float* __restrict__ gatev,
               u16* __restrict__ comb)
{
    __shared__ u16 Ks[3][64 * 64];
    __shared__ u16 Vs[3][64 * 64];
    __shared__ u16 Ps[4 * 16 * 64];   // 8KB; aliases norm_s / Mt

    const int t    = threadIdx.x;
    const int lane = t & 63;
    const int w    = t >> 6;
    const int lr   = lane & 15;
    const int kg   = lane >> 4;

    const int lin  = blockIdx.x + 16 * blockIdx.y + 256 * blockIdx.z;  // 0..511
    const int x    = lin & 7;
    const int gg   = lin >> 3;
    const int bh_i = x + 8 * (gg & 3);
    const int p    = gg >> 2;          // 0..15
    const int h    = bh_i & 15;
    const int b    = bh_i >> 4;
    const int qa = p, qb = 31 - p;
    const int nkt = qb + 1;

    const size_t bh = (size_t)b * NH + h;
    const u16* qp  = q  + bh * SEQ * HD;
    const u16* kp  = k  + bh * SEQ * HD;
    const u16* vtp = vt + bh * SEQ * HD;   // [d][s]

    int koff[4][2];
    #pragma unroll
    for (int fn = 0; fn < 4; ++fn)
        #pragma unroll
        for (int kk = 0; kk < 2; ++kk) {
            const int r = fn * 16 + lr;
            koff[fn][kk] = r * 64 + ((((kk << 2) + kg) ^ (r & 7)) << 3);
        }
    int pwoff[4][4];
    #pragma unroll
    for (int r = 0; r < 4; ++r) {
        const int row_p = kg * 4 + r;
        const int base_r = w * 1024 + row_p * 64 + (lr & 7);
        #pragma unroll
        for (int fn = 0; fn < 4; ++fn)
            pwoff[r][fn] = base_r + ((((fn << 1) + (lr >> 3)) ^ (row_p & 7)) << 3);
    }
    int pfoff[2];
    #pragma unroll
    for (int kk = 0; kk < 2; ++kk)
        pfoff[kk] = w * 1024 + lr * 64 + ((((kk << 2) + kg) ^ (lr & 7)) << 3);

    auto stageK = [&](int kt, u16* dst) {
        #pragma unroll
        for (int u = 0; u < 2; ++u) {
            const int cid = (u << 8) + t;
            const int row = cid >> 3, c16 = cid & 7;
            const int src = c16 ^ (row & 7);
            gload_lds16(kp + (size_t)(kt * 64 + row) * HD + (src << 3),
                        dst + (cid << 3));
        }
    };
    auto stageV = [&](int kt, u16* dst) {
        #pragma unroll
        for (int u = 0; u < 2; ++u) {
            const int cid = (u << 8) + t;
            const int row = cid >> 3, c16 = cid & 7;
            const int src = c16 ^ (row & 7);
            gload_lds16(vtp + (size_t)row * SEQ + kt * 64 + (src << 3),
                        dst + (cid << 3));
        }
    };

    float* norm_s = (float*)Ps;
    if (t < 64) norm_s[t] = normv[bh * HD + t];
    __syncthreads();

    const int rb2[2] = {qa * 64 + w * 16, qb * 64 + w * 16};
    short8 qatt[2][2], qmem[2][2];
    float nrrow[2];
    #pragma unroll
    for (int fm = 0; fm < 2; ++fm) {
        const u16* qrow = qp + (size_t)(rb2[fm] + lr) * HD;
        float nr = 0.f;
        #pragma unroll
        for (int kk = 0; kk < 2; ++kk) {
            const int dbase = kk * 32 + kg * 8;
            u16x8 raw = *(const u16x8*)(qrow + dbase);
            short8 sa, sm;
            #pragma unroll
            for (int i = 0; i < 8; ++i) {
                const float xx = bf2f(raw[i]);
                sa[i] = (short)f2bf(xx * (0.125f * LOG2E));
                const float e = (xx > 0.f) ? (xx + 1.f) : __expf(xx);
                sm[i] = (short)f2bf(e);
                nr = fmaf(e, norm_s[dbase + i], nr);
            }
            qatt[fm][kk] = sa; qmem[fm][kk] = sm;
        }
        nr += __shfl_xor(nr, 16);
        nr += __shfl_xor(nr, 32);
        nrrow[fm] = nr;
    }

    short8 ones8;
    {
        const short o = (lr == 0) ? (short)0x3F80 : (short)0;
        #pragma unroll
        for (int i = 0; i < 8; ++i) ones8[i] = o;
    }

    f32x4 oacc[2][4], lacc[2];
    #pragma unroll
    for (int fm = 0; fm < 2; ++fm) {
        #pragma unroll
        for (int fn = 0; fn < 4; ++fn) {
            f32x4 z = {0.f, 0.f, 0.f, 0.f};
            oacc[fm][fn] = z;
        }
        f32x4 z = {0.f, 0.f, 0.f, 0.f};
        lacc[fm] = z;
    }

    stageK(0, &Ks[0][0]);
    stageV(0, &Vs[0][0]);
    if (nkt > 1) {
        stageK(1, &Ks[1][0]);
        stageV(1, &Vs[1][0]);
        asm volatile("s_waitcnt vmcnt(4)" ::: "memory");
    } else {
        asm volatile("s_waitcnt vmcnt(0)" ::: "memory");
    }
    __builtin_amdgcn_sched_barrier(0);
    __builtin_amdgcn_s_barrier();

    int cur = 0;
    for (int kt = 0; kt < nkt; ++kt) {
        const u16* Kc = &Ks[cur][0];
        const u16* Vc = &Vs[cur][0];
        const int sl2 = (cur == 0) ? 2 : cur - 1;

        const bool more2 = (kt + 2 < nkt);
        if (more2) {
            stageK(kt + 2, &Ks[sl2][0]);
            stageV(kt + 2, &Vs[sl2][0]);
        }

        short8 kf[4][2], vf[4][2];
        #pragma unroll
        for (int fn = 0; fn < 4; ++fn)
            #pragma unroll
            for (int kk = 0; kk < 2; ++kk) {
                kf[fn][kk] = *(const short8*)&Kc[koff[fn][kk]];
                vf[fn][kk] = *(const short8*)&Vc[koff[fn][kk]];
            }

        auto do_fm = [&](auto FMC) {
            constexpr int fm = FMC.value;
            const int rb = rb2[fm];
            const bool diag = (kt == (fm ? qb : qa));
            f32x4 S[4];
            #pragma unroll
            for (int fn = 0; fn < 4; ++fn) {
                f32x4 z = {0.f, 0.f, 0.f, 0.f};
                S[fn] = z;
            }
            __builtin_amdgcn_s_setprio(1);
            #pragma unroll
            for (int fn = 0; fn < 4; ++fn)
                #pragma unroll
                for (int kk = 0; kk < 2; ++kk)
                    S[fn] = __builtin_amdgcn_mfma_f32_16x16x32_bf16(
                        qatt[fm][kk], kf[fn][kk], S[fn], 0, 0, 0);
            __builtin_amdgcn_s_setprio(0);

            #pragma unroll
            for (int fn = 0; fn < 4; ++fn) {
                const int kgl = kt * 64 + fn * 16 + lr;
                #pragma unroll
                for (int r = 0; r < 4; ++r) {
                    float pe = fast_exp2(S[fn][r]);
                    if (diag && kgl > rb + kg * 4 + r) pe = 0.f;
                    Ps[pwoff[r][fn]] = f2bf_trunc(pe);
                }
            }

            short8 pf[2];
            #pragma unroll
            for (int kk = 0; kk < 2; ++kk)
                pf[kk] = *(const short8*)&Ps[pfoff[kk]];
            __builtin_amdgcn_s_setprio(1);
            #pragma unroll
            for (int fnd = 0; fnd < 4; ++fnd)
                #pragma unroll
                for (int kk = 0; kk < 2; ++kk)
                    oacc[fm][fnd] = __builtin_amdgcn_mfma_f32_16x16x32_bf16(
                        pf[kk], vf[fnd][kk], oacc[fm][fnd], 0, 0, 0);
            #pragma unroll
            for (int kk = 0; kk < 2; ++kk)
                lacc[fm] = __builtin_amdgcn_mfma_f32_16x16x32_bf16(
                    pf[kk], ones8, lacc[fm], 0, 0, 0);
            __builtin_amdgcn_s_setprio(0);
        };
        if (kt <= qa) do_fm(std::integral_constant<int, 0>{});
        do_fm(std::integral_constant<int, 1>{});

        if (more2) {
            asm volatile("s_waitcnt vmcnt(4)" ::: "memory");
        } else {
            asm volatile("s_waitcnt vmcnt(0)" ::: "memory");
        }
        __builtin_amdgcn_sched_barrier(0);
        __builtin_amdgcn_s_barrier();

        cur = (cur == 2) ? 0 : cur + 1;
    }

    u16* MtS = Ps;
    {
        const float* Mb = memv + bh * HD * HD;
        #pragma unroll
        for (int u = 0; u < 2; ++u) {
            const int cid = (u << 8) + t;
            const int gd = cid & 63;
            const int e0 = (cid >> 6) << 3;
            float4 m0 = *(const float4*)(Mb + gd * HD + e0);
            float4 m1 = *(const float4*)(Mb + gd * HD + e0 + 4);
            float mv8[8];
            *(float4*)&mv8[0] = m0; *(float4*)&mv8[4] = m1;
            const int a = gd >> 3, bse = gd & 7;
            #pragma unroll
            for (int j = 0; j < 8; ++j)
                MtS[(e0 + j) * 64 + ((a ^ j) << 3) + bse] = f2bf(mv8[j]);
        }
    }
    __syncthreads();

    short8 mf2[4][2];
    #pragma unroll
    for (int fn = 0; fn < 4; ++fn)
        #pragma unroll
        for (int kk = 0; kk < 2; ++kk)
            mf2[fn][kk] = *(const short8*)&MtS[koff[fn][kk]];

    const float gte = gatev[h];
    const float g  = 1.f / (1.f + __expf(-gte));
    const float og = 1.f - g;

    #pragma unroll
    for (int fm = 0; fm < 2; ++fm) {
        f32x4 macc[4];
        #pragma unroll
        for (int fn = 0; fn < 4; ++fn) {
            f32x4 z = {0.f, 0.f, 0.f, 0.f};
            macc[fn] = z;
            #pragma unroll
            for (int kk = 0; kk < 2; ++kk)
                macc[fn] = __builtin_amdgcn_mfma_f32_16x16x32_bf16(
                    qmem[fm][kk], mf2[fn][kk], macc[fn], 0, 0, 0);
        }
        #pragma unroll
        for (int r = 0; r < 4; ++r) {
            const int rt  = kg * 4 + r;
            const float lsum  = __shfl(lacc[fm][r], lane & 48);
            const float linv  = 1.f / lsum;
            const float nrd   = __shfl(nrrow[fm], (lane & 48) | rt);
            const float nrinv = 1.f / (nrd + 1e-6f);
            const int qg = rb2[fm] + rt;
            u16* crow = comb + ((size_t)b * SEQ + qg) * DIM + h * HD;
            #pragma unroll
            for (int fn = 0; fn < 4; ++fn)
                crow[fn * 16 + lr] = f2bf(
                    g * (macc[fn][r] * nrinv) + og * (oacc[fm][fn][r] * linv));
        }
    }
}

// ---------------------------------------------------------------------------
// Memory write partials via MFMA. r18-identical.
// ---------------------------------------------------------------------------
__global__ __launch_bounds__(256)
void memwrite_mfma(const u16* __restrict__ k,
                   const u16* __restrict__ vt,
                   float* __restrict__ part,
                   float* __restrict__ pnorm)
{
    __shared__ u16 KelT[64 * 64];
    __shared__ u16 Vs[64 * 64];

    const int ch = blockIdx.x;   // 0..15 (128-s chunk)
    const int bh = blockIdx.y;   // 0..31
    const int t    = threadIdx.x;
    const int lane = t & 63;
    const int w    = t >> 6;
    const int lr   = lane & 15;
    const int kg   = lane >> 4;

    const u16* kb  = k  + (size_t)bh * SEQ * HD + (size_t)ch * 128 * HD;
    const u16* vtb = vt + (size_t)bh * SEQ * HD + (size_t)ch * 128;   // [d][s]

    int aoff[2];
    #pragma unroll
    for (int kk = 0; kk < 2; ++kk) {
        const int r = w * 16 + lr;
        aoff[kk] = r * 64 + ((((kk << 2) + kg) ^ (r & 7)) << 3);
    }
    int boff[4][2];
    #pragma unroll
    for (int fn = 0; fn < 4; ++fn)
        #pragma unroll
        for (int kk = 0; kk < 2; ++kk) {
            const int r = fn * 16 + lr;
            boff[fn][kk] = r * 64 + ((((kk << 2) + kg) ^ (r & 7)) << 3);
        }

    short8 ones8;
    {
        const short o = (lr == 0) ? (short)0x3F80 : (short)0;
        #pragma unroll
        for (int i = 0; i < 8; ++i) ones8[i] = o;
    }

    f32x4 acc[4], lacc;
    #pragma unroll
    for (int fn = 0; fn < 4; ++fn) {
        f32x4 z = {0.f, 0.f, 0.f, 0.f};
        acc[fn] = z;
    }
    { f32x4 z = {0.f, 0.f, 0.f, 0.f}; lacc = z; }

    for (int st = 0; st < 2; ++st) {
        __syncthreads();
        #pragma unroll
        for (int u = 0; u < 2; ++u) {
            const int cid = (u << 8) + t;
            const int row = cid >> 3, c16 = cid & 7;
            const int src = c16 ^ (row & 7);
            gload_lds16(vtb + (size_t)row * SEQ + st * 64 + (src << 3),
                        &Vs[cid << 3]);
        }
        #pragma unroll
        for (int u = 0; u < 2; ++u) {
            const int cid = (u << 8) + t;
            const int krow = cid & 63;
            const int d0   = (cid >> 6) << 3;
            u16x8 kv = *(const u16x8*)(kb + (size_t)(st * 64 + krow) * HD + d0);
            const int a = krow >> 3, bse = krow & 7;
            #pragma unroll
            for (int j = 0; j < 8; ++j) {
                const float kf = bf2f(kv[j]);
                const float e = (kf > 0.f) ? kf + 1.f : __expf(kf);
                KelT[(d0 + j) * 64 + ((a ^ ((d0 + j) & 7)) << 3) + bse] = f2bf(e);
            }
        }
        __syncthreads();

        short8 af[2];
        #pragma unroll
        for (int kk = 0; kk < 2; ++kk)
            af[kk] = *(const short8*)&KelT[aoff[kk]];
        #pragma unroll
        for (int fn = 0; fn < 4; ++fn)
            #pragma unroll
            for (int kk = 0; kk < 2; ++kk) {
                short8 bfv = *(const short8*)&Vs[boff[fn][kk]];
                acc[fn] = __builtin_amdgcn_mfma_f32_16x16x32_bf16(
                    af[kk], bfv, acc[fn], 0, 0, 0);
            }
        #pragma unroll
        for (int kk = 0; kk < 2; ++kk)
            lacc = __builtin_amdgcn_mfma_f32_16x16x32_bf16(
                af[kk], ones8, lacc, 0, 0, 0);
    }

    float* po = part + ((size_t)bh * 16 + ch) * 4096;
    #pragma unroll
    for (int r = 0; r < 4; ++r) {
        const int d = w * 16 + kg * 4 + r;
        #pragma unroll
        for (int fn = 0; fn < 4; ++fn)
            po[d * 64 + fn * 16 + lr] = acc[fn][r];
    }
    if (lr == 0) {
        #pragma unroll
        for (int r = 0; r < 4; ++r)
            pnorm[((size_t)bh * 16 + ch) * 64 + w * 16 + kg * 4 + r] = lacc[r];
    }
}

// ---------------------------------------------------------------------------
extern "C" void kernel_launch(void* const* d_in, const int* in_sizes, int n_in,
                              void* d_out, int out_size, void* d_ws, size_t ws_size,
                              hipStream_t stream)
{
    const float* x     = (const float*)d_in[0];
    const float* memv  = (const float*)d_in[1];
    const float* normv = (const float*)d_in[2];
    const float* Wq    = (const float*)d_in[3];
    const float* Wk    = (const float*)d_in[4];
    const float* Wv    = (const float*)d_in[5];
    const float* Wo    = (const float*)d_in[6];
    const float* gate  = (const float*)d_in[7];
    float* out = (float*)d_out;

    u16* xbf  = (u16*)d_ws;                    // 2^22 elems
    u16* wbf  = xbf + ((size_t)1 << 22);       // 4 * 2^20
    u16* qkv  = wbf + ((size_t)4 << 20);       // 3 * 2^22 (q, k, vT)
    u16* comb = qkv + ((size_t)3 << 22);       // 2^22
    float* part  = (float*)(comb + ((size_t)1 << 22));   // 2^21 f32 (8 MB)
    float* pnorm = part + ((size_t)1 << 21);             // 32768 f32

    u16* qbf = qkv;
    u16* kbf = qkv + ((size_t)1 << 22);
    u16* vtb = qkv + ((size_t)2 << 22);        // V^T [b,h,d,s]

    float* new_mem  = out + (size_t)NB * SEQ * DIM;
    float* new_norm = new_mem + (size_t)NB * NH * HD * HD;

    conv_bf16<<<dim3(4096), 256, 0, stream>>>(x, Wq, Wk, Wv, Wo, xbf, wbf);
    gemm_lds<0, 4><<<dim3(32, 8, 3), 256, 0, stream>>>(
        xbf, wbf, qkv, nullptr,
        nullptr, nullptr, nullptr, nullptr, nullptr, nullptr);
    attn_mfma<<<dim3(16, 16, 2), 256, 0, stream>>>(qbf, kbf, vtb, memv, normv,
                                                   gate, comb);
    memwrite_mfma<<<dim3(16, 32), 256, 0, stream>>>(kbf, vtb, part, pnorm);
    gemm_lds<1, 2><<<dim3(64, 9, 1), 256, 0, stream>>>(
        comb, wbf + ((size_t)3 << 20), nullptr, out,
        part, pnorm, memv, normv, new_mem, new_norm);
}

// Round 21
// 116.396 us; speedup vs baseline: 1.2035x; 1.0010x over previous
//
#include <hip/hip_runtime.h>
#include <hip/hip_bf16.h>
#include <math.h>
#include <type_traits>

#define DIM 1024
#define NH 16
#define HD 64
#define NB 2
#define SEQ 2048

typedef unsigned short u16;
typedef short short8 __attribute__((ext_vector_type(8)));
typedef unsigned short u16x8 __attribute__((ext_vector_type(8)));
typedef unsigned short u16x4v __attribute__((ext_vector_type(4)));
typedef float f32x4 __attribute__((ext_vector_type(4)));

#define LOG2E 1.44269504f

__device__ __forceinline__ u16 f2bf(float f) {
    __hip_bfloat16 h = __float2bfloat16(f);
    return __builtin_bit_cast(u16, h);
}
__device__ __forceinline__ float bf2f(u16 u) {
    return __uint_as_float(((unsigned)u) << 16);
}
// truncating f32->bf16 (P values only: <=0.4% rel err, self-consistent with l)
__device__ __forceinline__ u16 f2bf_trunc(float f) {
    return (u16)(__float_as_uint(f) >> 16);
}
// raw v_exp_f32 (exp2): used ONLY in the attn softmax hot loop (r14-verified).
__device__ __forceinline__ float fast_exp2(float x) {
    float r;
    asm("v_exp_f32 %0, %1" : "=v"(r) : "v"(x));
    return r;
}

// global -> LDS direct async copy, 16B per lane (dest linear per wave).
__device__ __forceinline__ void gload_lds16(const u16* g, u16* l) {
    __builtin_amdgcn_global_load_lds(
        (const __attribute__((address_space(1))) unsigned int*)g,
        (__attribute__((address_space(3))) unsigned int*)l, 16, 0, 0);
}

// ---------------------------------------------------------------------------
// fp32 -> bf16 conversion pass, flat grid (right-sized: 4096 blocks).
// ---------------------------------------------------------------------------
__global__ __launch_bounds__(256)
void conv_bf16(const float* __restrict__ x,
               const float* __restrict__ wq, const float* __restrict__ wk,
               const float* __restrict__ wv, const float* __restrict__ wo,
               u16* __restrict__ xbf, u16* __restrict__ wbf)
{
    const int idx8 = (blockIdx.x * 256 + threadIdx.x) * 8;
    const float* src; u16* dst; int off;
    if (idx8 < (1 << 22)) {
        src = x; dst = xbf; off = idx8;
    } else {
        const int wi  = idx8 - (1 << 22);
        const int sel = wi >> 20;
        src = (sel == 0) ? wq : (sel == 1) ? wk : (sel == 2) ? wv : wo;
        dst = wbf + ((size_t)sel << 20);
        off = wi & ((1 << 20) - 1);
    }
    float4 a = *(const float4*)(src + off);
    float4 b = *(const float4*)(src + off + 4);
    u16x8 o;
    o[0] = f2bf(a.x); o[1] = f2bf(a.y); o[2] = f2bf(a.z); o[3] = f2bf(a.w);
    o[4] = f2bf(b.x); o[5] = f2bf(b.y); o[6] = f2bf(b.z); o[7] = f2bf(b.w);
    *(u16x8*)(dst + off) = o;
}

// ---------------------------------------------------------------------------
// bf16 GEMM via global_load_lds (m97 structure). r18-identical.
// MODE 0: z=0(q)/1(k) head-split [b,h,s,hd] bf16; z=2(v) transposed [b,h,d,s].
// MODE 1: fp32 flat [b,s,e]; blockIdx.y==8 & x<32 -> fused memwrite_reduce.
// ---------------------------------------------------------------------------
template<int MODE, int FM>
__global__ __launch_bounds__(256)
void gemm_lds(const u16* __restrict__ X, const u16* __restrict__ Wall,
              u16* __restrict__ Obf, float* __restrict__ Of,
              const float* __restrict__ part, const float* __restrict__ pnorm,
              const float* __restrict__ memv, const float* __restrict__ normv,
              float* __restrict__ new_mem, float* __restrict__ new_norm)
{
    constexpr int MT = FM * 32;
    __shared__ u16 As[MT * 64];
    __shared__ u16 Bs[128 * 64];

    if (MODE == 1 && blockIdx.y == 8) {
        if (blockIdx.x >= 32) return;
        const int bh = blockIdx.x;
        const int t  = threadIdx.x;
        #pragma unroll
        for (int u = 0; u < 16; ++u) {
            const int fl = t + (u << 8);
            float s = memv[(size_t)bh * 4096 + fl];
            #pragma unroll
            for (int ch = 0; ch < 16; ++ch)
                s += part[((size_t)bh * 16 + ch) * 4096 + fl];
            new_mem[(size_t)bh * 4096 + fl] = s;
        }
        if (t < 64) {
            float s = normv[(size_t)bh * 64 + t];
            #pragma unroll
            for (int ch = 0; ch < 16; ++ch)
                s += pnorm[((size_t)bh * 16 + ch) * 64 + t];
            new_norm[(size_t)bh * 64 + t] = s;
        }
        return;
    }

    const int t    = threadIdx.x;
    const int lane = t & 63;
    const int wave = t >> 6;
    const int wm = wave >> 1, wn = wave & 1;
    const int lr = lane & 15, kg = lane >> 4;
    const int m_base = blockIdx.x * MT;
    const int n_base = blockIdx.y * 128;

    const u16* Xb = X + (size_t)m_base * DIM;
    const u16* Wb = Wall + (MODE == 0 ? ((size_t)blockIdx.z << 20) : (size_t)0)
                         + (size_t)n_base * DIM;

    f32x4 acc[FM][4];
    #pragma unroll
    for (int i = 0; i < FM; ++i)
        #pragma unroll
        for (int j = 0; j < 4; ++j) {
            f32x4 z = {0.f, 0.f, 0.f, 0.f};
            acc[i][j] = z;
        }

    for (int k0 = 0; k0 < DIM; k0 += 64) {
        __syncthreads();
        #pragma unroll
        for (int u = 0; u < FM; ++u) {
            const int cid = (u << 8) + t;
            const int row = cid >> 3, c16 = cid & 7;
            const int src = c16 ^ (row & 7);
            gload_lds16(Xb + (size_t)row * DIM + k0 + (src << 3), &As[cid << 3]);
        }
        #pragma unroll
        for (int u = 0; u < 4; ++u) {
            const int cid = (u << 8) + t;
            const int row = cid >> 3, c16 = cid & 7;
            const int src = c16 ^ (row & 7);
            gload_lds16(Wb + (size_t)row * DIM + k0 + (src << 3), &Bs[cid << 3]);
        }
        __syncthreads();

        #pragma unroll
        for (int kh = 0; kh < 2; ++kh) {
            short8 afrag[FM], bfrag[4];
            #pragma unroll
            for (int fm = 0; fm < FM; ++fm) {
                const int r = wm * (FM * 16) + fm * 16 + lr;
                const int c = (kh << 2) + kg;
                afrag[fm] = *(const short8*)&As[r * 64 + (((c) ^ (r & 7)) << 3)];
            }
            #pragma unroll
            for (int fn = 0; fn < 4; ++fn) {
                const int r = wn * 64 + fn * 16 + lr;
                const int c = (kh << 2) + kg;
                bfrag[fn] = *(const short8*)&Bs[r * 64 + (((c) ^ (r & 7)) << 3)];
            }
            #pragma unroll
            for (int fm = 0; fm < FM; ++fm)
                #pragma unroll
                for (int fn = 0; fn < 4; ++fn)
                    acc[fm][fn] = __builtin_amdgcn_mfma_f32_16x16x32_bf16(
                        afrag[fm], bfrag[fn], acc[fm][fn], 0, 0, 0);
        }
    }

    u16* O0 = (MODE == 0) ? Obf + ((size_t)blockIdx.z << 22) : nullptr;
    if (MODE == 0 && blockIdx.z == 2) {
        #pragma unroll
        for (int fm = 0; fm < FM; ++fm) {
            const int m0 = m_base + wm * (FM * 16) + fm * 16 + kg * 4;
            const int b_ = m0 >> 11;
            const int s0 = m0 & (SEQ - 1);
            #pragma unroll
            for (int fn = 0; fn < 4; ++fn) {
                const int n  = n_base + wn * 64 + fn * 16 + lr;
                const int h_ = n >> 6, d_ = n & 63;
                u16x4v pk;
                #pragma unroll
                for (int i = 0; i < 4; ++i) pk[i] = f2bf(acc[fm][fn][i]);
                *(u16x4v*)(O0 + (((size_t)b_ * NH + h_) * HD + d_) * SEQ + s0) = pk;
            }
        }
    } else {
        #pragma unroll
        for (int fm = 0; fm < FM; ++fm) {
            const int mrow0 = m_base + wm * (FM * 16) + fm * 16 + kg * 4;
            #pragma unroll
            for (int i = 0; i < 4; ++i) {
                const int m = mrow0 + i;
                const int b = m >> 11;
                const int s = m & (SEQ - 1);
                #pragma unroll
                for (int fn = 0; fn < 4; ++fn) {
                    const int n = n_base + wn * 64 + fn * 16 + lr;
                    const float val = acc[fm][fn][i];
                    if (MODE == 0)
                        O0[(((size_t)b * NH + (n >> 6)) * SEQ + s) * HD + (n & 63)] =
                            f2bf(val);
                    else
                        Of[((size_t)b * SEQ + s) * DIM + n] = val;
                }
            }
        }
    }
}

// ---------------------------------------------------------------------------
// MFMA flash attention + memory read + gated combine. r18/r20 structure with
// ONE change: per-fm Ps halves (fm<<12 offset) — the shared per-wave Ps made
// fm1's P-writes depend on fm0's P-reads, serializing the two passes; with
// disjoint regions the scheduler can issue fm1's QK^T under fm0's P round
// trip. LDS 57344 -> 65536 B (still 2 blocks/CU).
// r19: no fm-split across waves (uniformity). r13: no memwrite interleave.
// r11: 64-stride LDS rows. r10: no KV-split. (256,2): tighter bounds spill.
// ---------------------------------------------------------------------------
__global__ __launch_bounds__(256, 2)
void attn_mfma(const u16* __restrict__ q,
               const u16* __restrict__ k,
               const u16* __restrict__ vt,
               const float* __restrict__ memv,
               const float* __restrict__ normv,
               const float* __restrict__ gatev,
               u16* __restrict__ comb)
{
    __shared__ u16 Ks[3][64 * 64];
    __shared__ u16 Vs[3][64 * 64];
    __shared__ u16 Ps[2 * 4 * 16 * 64];   // 16KB: per-fm 8KB halves

    const int t    = threadIdx.x;
    const int lane = t & 63;
    const int w    = t >> 6;
    const int lr   = lane & 15;
    const int kg   = lane >> 4;

    const int lin  = blockIdx.x + 16 * blockIdx.y + 256 * blockIdx.z;  // 0..511
    const int x    = lin & 7;
    const int gg   = lin >> 3;
    const int bh_i = x + 8 * (gg & 3);
    const int p    = gg >> 2;          // 0..15
    const int h    = bh_i & 15;
    const int b    = bh_i >> 4;
    const int qa = p, qb = 31 - p;
    const int nkt = qb + 1;

    const size_t bh = (size_t)b * NH + h;
    const u16* qp  = q  + bh * SEQ * HD;
    const u16* kp  = k  + bh * SEQ * HD;
    const u16* vtp = vt + bh * SEQ * HD;   // [d][s]

    int koff[4][2];
    #pragma unroll
    for (int fn = 0; fn < 4; ++fn)
        #pragma unroll
        for (int kk = 0; kk < 2; ++kk) {
            const int r = fn * 16 + lr;
            koff[fn][kk] = r * 64 + ((((kk << 2) + kg) ^ (r & 7)) << 3);
        }
    int pwoff[4][4];
    #pragma unroll
    for (int r = 0; r < 4; ++r) {
        const int row_p = kg * 4 + r;
        const int base_r = w * 1024 + row_p * 64 + (lr & 7);
        #pragma unroll
        for (int fn = 0; fn < 4; ++fn)
            pwoff[r][fn] = base_r + ((((fn << 1) + (lr >> 3)) ^ (row_p & 7)) << 3);
    }
    int pfoff[2];
    #pragma unroll
    for (int kk = 0; kk < 2; ++kk)
        pfoff[kk] = w * 1024 + lr * 64 + ((((kk << 2) + kg) ^ (lr & 7)) << 3);

    auto stageK = [&](int kt, u16* dst) {
        #pragma unroll
        for (int u = 0; u < 2; ++u) {
            const int cid = (u << 8) + t;
            const int row = cid >> 3, c16 = cid & 7;
            const int src = c16 ^ (row & 7);
            gload_lds16(kp + (size_t)(kt * 64 + row) * HD + (src << 3),
                        dst + (cid << 3));
        }
    };
    auto stageV = [&](int kt, u16* dst) {
        #pragma unroll
        for (int u = 0; u < 2; ++u) {
            const int cid = (u << 8) + t;
            const int row = cid >> 3, c16 = cid & 7;
            const int src = c16 ^ (row & 7);
            gload_lds16(vtp + (size_t)row * SEQ + kt * 64 + (src << 3),
                        dst + (cid << 3));
        }
    };

    float* norm_s = (float*)Ps;
    if (t < 64) norm_s[t] = normv[bh * HD + t];
    __syncthreads();

    const int rb2[2] = {qa * 64 + w * 16, qb * 64 + w * 16};
    short8 qatt[2][2], qmem[2][2];
    float nrrow[2];
    #pragma unroll
    for (int fm = 0; fm < 2; ++fm) {
        const u16* qrow = qp + (size_t)(rb2[fm] + lr) * HD;
        float nr = 0.f;
        #pragma unroll
        for (int kk = 0; kk < 2; ++kk) {
            const int dbase = kk * 32 + kg * 8;
            u16x8 raw = *(const u16x8*)(qrow + dbase);
            short8 sa, sm;
            #pragma unroll
            for (int i = 0; i < 8; ++i) {
                const float xx = bf2f(raw[i]);
                sa[i] = (short)f2bf(xx * (0.125f * LOG2E));
                const float e = (xx > 0.f) ? (xx + 1.f) : __expf(xx);
                sm[i] = (short)f2bf(e);
                nr = fmaf(e, norm_s[dbase + i], nr);
            }
            qatt[fm][kk] = sa; qmem[fm][kk] = sm;
        }
        nr += __shfl_xor(nr, 16);
        nr += __shfl_xor(nr, 32);
        nrrow[fm] = nr;
    }

    short8 ones8;
    {
        const short o = (lr == 0) ? (short)0x3F80 : (short)0;
        #pragma unroll
        for (int i = 0; i < 8; ++i) ones8[i] = o;
    }

    f32x4 oacc[2][4], lacc[2];
    #pragma unroll
    for (int fm = 0; fm < 2; ++fm) {
        #pragma unroll
        for (int fn = 0; fn < 4; ++fn) {
            f32x4 z = {0.f, 0.f, 0.f, 0.f};
            oacc[fm][fn] = z;
        }
        f32x4 z = {0.f, 0.f, 0.f, 0.f};
        lacc[fm] = z;
    }

    stageK(0, &Ks[0][0]);
    stageV(0, &Vs[0][0]);
    if (nkt > 1) {
        stageK(1, &Ks[1][0]);
        stageV(1, &Vs[1][0]);
        asm volatile("s_waitcnt vmcnt(4)" ::: "memory");
    } else {
        asm volatile("s_waitcnt vmcnt(0)" ::: "memory");
    }
    __builtin_amdgcn_sched_barrier(0);
    __builtin_amdgcn_s_barrier();

    int cur = 0;
    for (int kt = 0; kt < nkt; ++kt) {
        const u16* Kc = &Ks[cur][0];
        const u16* Vc = &Vs[cur][0];
        const int sl2 = (cur == 0) ? 2 : cur - 1;

        const bool more2 = (kt + 2 < nkt);
        if (more2) {
            stageK(kt + 2, &Ks[sl2][0]);
            stageV(kt + 2, &Vs[sl2][0]);
        }

        short8 kf[4][2], vf[4][2];
        #pragma unroll
        for (int fn = 0; fn < 4; ++fn)
            #pragma unroll
            for (int kk = 0; kk < 2; ++kk) {
                kf[fn][kk] = *(const short8*)&Kc[koff[fn][kk]];
                vf[fn][kk] = *(const short8*)&Vc[koff[fn][kk]];
            }

        auto do_fm = [&](auto FMC) {
            constexpr int fm = FMC.value;
            constexpr int psbase = fm << 12;   // disjoint per-fm Ps half
            const int rb = rb2[fm];
            const bool diag = (kt == (fm ? qb : qa));
            f32x4 S[4];
            #pragma unroll
            for (int fn = 0; fn < 4; ++fn) {
                f32x4 z = {0.f, 0.f, 0.f, 0.f};
                S[fn] = z;
            }
            __builtin_amdgcn_s_setprio(1);
            #pragma unroll
            for (int fn = 0; fn < 4; ++fn)
                #pragma unroll
                for (int kk = 0; kk < 2; ++kk)
                    S[fn] = __builtin_amdgcn_mfma_f32_16x16x32_bf16(
                        qatt[fm][kk], kf[fn][kk], S[fn], 0, 0, 0);
            __builtin_amdgcn_s_setprio(0);

            #pragma unroll
            for (int fn = 0; fn < 4; ++fn) {
                const int kgl = kt * 64 + fn * 16 + lr;
                #pragma unroll
                for (int r = 0; r < 4; ++r) {
                    float pe = fast_exp2(S[fn][r]);
                    if (diag && kgl > rb + kg * 4 + r) pe = 0.f;
                    Ps[psbase + pwoff[r][fn]] = f2bf_trunc(pe);
                }
            }

            short8 pf[2];
            #pragma unroll
            for (int kk = 0; kk < 2; ++kk)
                pf[kk] = *(const short8*)&Ps[psbase + pfoff[kk]];
            __builtin_amdgcn_s_setprio(1);
            #pragma unroll
            for (int fnd = 0; fnd < 4; ++fnd)
                #pragma unroll
                for (int kk = 0; kk < 2; ++kk)
                    oacc[fm][fnd] = __builtin_amdgcn_mfma_f32_16x16x32_bf16(
                        pf[kk], vf[fnd][kk], oacc[fm][fnd], 0, 0, 0);
            #pragma unroll
            for (int kk = 0; kk < 2; ++kk)
                lacc[fm] = __builtin_amdgcn_mfma_f32_16x16x32_bf16(
                    pf[kk], ones8, lacc[fm], 0, 0, 0);
            __builtin_amdgcn_s_setprio(0);
        };
        if (kt <= qa) do_fm(std::integral_constant<int, 0>{});
        do_fm(std::integral_constant<int, 1>{});

        if (more2) {
            asm volatile("s_waitcnt vmcnt(4)" ::: "memory");
        } else {
            asm volatile("s_waitcnt vmcnt(0)" ::: "memory");
        }
        __builtin_amdgcn_sched_barrier(0);
        __builtin_amdgcn_s_barrier();

        cur = (cur == 2) ? 0 : cur + 1;
    }

    u16* MtS = Ps;
    {
        const float* Mb = memv + bh * HD * HD;
        #pragma unroll
        for (int u = 0; u < 2; ++u) {
            const int cid = (u << 8) + t;
            const int gd = cid & 63;
            const int e0 = (cid >> 6) << 3;
            float4 m0 = *(const float4*)(Mb + gd * HD + e0);
            float4 m1 = *(const float4*)(Mb + gd * HD + e0 + 4);
            float mv8[8];
            *(float4*)&mv8[0] = m0; *(float4*)&mv8[4] = m1;
            const int a = gd >> 3, bse = gd & 7;
            #pragma unroll
            for (int j = 0; j < 8; ++j)
                MtS[(e0 + j) * 64 + ((a ^ j) << 3) + bse] = f2bf(mv8[j]);
        }
    }
    __syncthreads();

    short8 mf2[4][2];
    #pragma unroll
    for (int fn = 0; fn < 4; ++fn)
        #pragma unroll
        for (int kk = 0; kk < 2; ++kk)
            mf2[fn][kk] = *(const short8*)&MtS[koff[fn][kk]];

    const float gte = gatev[h];
    const float g  = 1.f / (1.f + __expf(-gte));
    const float og = 1.f - g;

    #pragma unroll
    for (int fm = 0; fm < 2; ++fm) {
        f32x4 macc[4];
        #pragma unroll
        for (int fn = 0; fn < 4; ++fn) {
            f32x4 z = {0.f, 0.f, 0.f, 0.f};
            macc[fn] = z;
            #pragma unroll
            for (int kk = 0; kk < 2; ++kk)
                macc[fn] = __builtin_amdgcn_mfma_f32_16x16x32_bf16(
                    qmem[fm][kk], mf2[fn][kk], macc[fn], 0, 0, 0);
        }
        #pragma unroll
        for (int r = 0; r < 4; ++r) {
            const int rt  = kg * 4 + r;
            const float lsum  = __shfl(lacc[fm][r], lane & 48);
            const float linv  = 1.f / lsum;
            const float nrd   = __shfl(nrrow[fm], (lane & 48) | rt);
            const float nrinv = 1.f / (nrd + 1e-6f);
            const int qg = rb2[fm] + rt;
            u16* crow = comb + ((size_t)b * SEQ + qg) * DIM + h * HD;
            #pragma unroll
            for (int fn = 0; fn < 4; ++fn)
                crow[fn * 16 + lr] = f2bf(
                    g * (macc[fn][r] * nrinv) + og * (oacc[fm][fn][r] * linv));
        }
    }
}

// ---------------------------------------------------------------------------
// Memory write partials via MFMA. r18-identical.
// ---------------------------------------------------------------------------
__global__ __launch_bounds__(256)
void memwrite_mfma(const u16* __restrict__ k,
                   const u16* __restrict__ vt,
                   float* __restrict__ part,
                   float* __restrict__ pnorm)
{
    __shared__ u16 KelT[64 * 64];
    __shared__ u16 Vs[64 * 64];

    const int ch = blockIdx.x;   // 0..15 (128-s chunk)
    const int bh = blockIdx.y;   // 0..31
    const int t    = threadIdx.x;
    const int lane = t & 63;
    const int w    = t >> 6;
    const int lr   = lane & 15;
    const int kg   = lane >> 4;

    const u16* kb  = k  + (size_t)bh * SEQ * HD + (size_t)ch * 128 * HD;
    const u16* vtb = vt + (size_t)bh * SEQ * HD + (size_t)ch * 128;   // [d][s]

    int aoff[2];
    #pragma unroll
    for (int kk = 0; kk < 2; ++kk) {
        const int r = w * 16 + lr;
        aoff[kk] = r * 64 + ((((kk << 2) + kg) ^ (r & 7)) << 3);
    }
    int boff[4][2];
    #pragma unroll
    for (int fn = 0; fn < 4; ++fn)
        #pragma unroll
        for (int kk = 0; kk < 2; ++kk) {
            const int r = fn * 16 + lr;
            boff[fn][kk] = r * 64 + ((((kk << 2) + kg) ^ (r & 7)) << 3);
        }

    short8 ones8;
    {
        const short o = (lr == 0) ? (short)0x3F80 : (short)0;
        #pragma unroll
        for (int i = 0; i < 8; ++i) ones8[i] = o;
    }

    f32x4 acc[4], lacc;
    #pragma unroll
    for (int fn = 0; fn < 4; ++fn) {
        f32x4 z = {0.f, 0.f, 0.f, 0.f};
        acc[fn] = z;
    }
    { f32x4 z = {0.f, 0.f, 0.f, 0.f}; lacc = z; }

    for (int st = 0; st < 2; ++st) {
        __syncthreads();
        #pragma unroll
        for (int u = 0; u < 2; ++u) {
            const int cid = (u << 8) + t;
            const int row = cid >> 3, c16 = cid & 7;
            const int src = c16 ^ (row & 7);
            gload_lds16(vtb + (size_t)row * SEQ + st * 64 + (src << 3),
                        &Vs[cid << 3]);
        }
        #pragma unroll
        for (int u = 0; u < 2; ++u) {
            const int cid = (u << 8) + t;
            const int krow = cid & 63;
            const int d0   = (cid >> 6) << 3;
            u16x8 kv = *(const u16x8*)(kb + (size_t)(st * 64 + krow) * HD + d0);
            const int a = krow >> 3, bse = krow & 7;
            #pragma unroll
            for (int j = 0; j < 8; ++j) {
                const float kf = bf2f(kv[j]);
                const float e = (kf > 0.f) ? kf + 1.f : __expf(kf);
                KelT[(d0 + j) * 64 + ((a ^ ((d0 + j) & 7)) << 3) + bse] = f2bf(e);
            }
        }
        __syncthreads();

        short8 af[2];
        #pragma unroll
        for (int kk = 0; kk < 2; ++kk)
            af[kk] = *(const short8*)&KelT[aoff[kk]];
        #pragma unroll
        for (int fn = 0; fn < 4; ++fn)
            #pragma unroll
            for (int kk = 0; kk < 2; ++kk) {
                short8 bfv = *(const short8*)&Vs[boff[fn][kk]];
                acc[fn] = __builtin_amdgcn_mfma_f32_16x16x32_bf16(
                    af[kk], bfv, acc[fn], 0, 0, 0);
            }
        #pragma unroll
        for (int kk = 0; kk < 2; ++kk)
            lacc = __builtin_amdgcn_mfma_f32_16x16x32_bf16(
                af[kk], ones8, lacc, 0, 0, 0);
    }

    float* po = part + ((size_t)bh * 16 + ch) * 4096;
    #pragma unroll
    for (int r = 0; r < 4; ++r) {
        const int d = w * 16 + kg * 4 + r;
        #pragma unroll
        for (int fn = 0; fn < 4; ++fn)
            po[d * 64 + fn * 16 + lr] = acc[fn][r];
    }
    if (lr == 0) {
        #pragma unroll
        for (int r = 0; r < 4; ++r)
            pnorm[((size_t)bh * 16 + ch) * 64 + w * 16 + kg * 4 + r] = lacc[r];
    }
}

// ---------------------------------------------------------------------------
extern "C" void kernel_launch(void* const* d_in, const int* in_sizes, int n_in,
                              void* d_out, int out_size, void* d_ws, size_t ws_size,
                              hipStream_t stream)
{
    const float* x     = (const float*)d_in[0];
    const float* memv  = (const float*)d_in[1];
    const float* normv = (const float*)d_in[2];
    const float* Wq    = (const float*)d_in[3];
    const float* Wk    = (const float*)d_in[4];
    const float* Wv    = (const float*)d_in[5];
    const float* Wo    = (const float*)d_in[6];
    const float* gate  = (const float*)d_in[7];
    float* out = (float*)d_out;

    u16* xbf  = (u16*)d_ws;                    // 2^22 elems
    u16* wbf  = xbf + ((size_t)1 << 22);       // 4 * 2^20
    u16* qkv  = wbf + ((size_t)4 << 20);       // 3 * 2^22 (q, k, vT)
    u16* comb = qkv + ((size_t)3 << 22);       // 2^22
    float* part  = (float*)(comb + ((size_t)1 << 22));   // 2^21 f32 (8 MB)
    float* pnorm = part + ((size_t)1 << 21);             // 32768 f32

    u16* qbf = qkv;
    u16* kbf = qkv + ((size_t)1 << 22);
    u16* vtb = qkv + ((size_t)2 << 22);        // V^T [b,h,d,s]

    float* new_mem  = out + (size_t)NB * SEQ * DIM;
    float* new_norm = new_mem + (size_t)NB * NH * HD * HD;

    conv_bf16<<<dim3(4096), 256, 0, stream>>>(x, Wq, Wk, Wv, Wo, xbf, wbf);
    gemm_lds<0, 4><<<dim3(32, 8, 3), 256, 0, stream>>>(
        xbf, wbf, qkv, nullptr,
        nullptr, nullptr, nullptr, nullptr, nullptr, nullptr);
    attn_mfma<<<dim3(16, 16, 2), 256, 0, stream>>>(qbf, kbf, vtb, memv, normv,
                                                   gate, comb);
    memwrite_mfma<<<dim3(16, 32), 256, 0, stream>>>(kbf, vtb, part, pnorm);
    gemm_lds<1, 2><<<dim3(64, 9, 1), 256, 0, stream>>>(
        comb, wbf + ((size_t)3 << 20), nullptr, out,
        part, pnorm, memv, normv, new_mem, new_norm);
}